// Round 11
// baseline (47.831 us; speedup 1.0000x reference)
//
#include <hip/hip_runtime.h>

typedef __attribute__((ext_vector_type(8))) short bf16x8_t;   // 8 bf16 (4 VGPRs)
typedef __attribute__((ext_vector_type(4))) float f32x4_t;    // MFMA accumulator
typedef __attribute__((ext_vector_type(2))) float f32x2_t;    // packed f32 pair

__device__ __forceinline__ unsigned short f2bf(float f) {
    union { float f; unsigned int i; } v; v.f = f;
    unsigned int u = v.i;
    return (unsigned short)((u + 0x7FFFu + ((u >> 16) & 1u)) >> 16);   // RNE
}

__device__ __forceinline__ unsigned int cvt_pk_bf16(float lo, float hi) {
    unsigned int r;
    asm("v_cvt_pk_bf16_f32 %0, %1, %2" : "=v"(r) : "v"(lo), "v"(hi));
    return r;
}

#define LD4(p) (*reinterpret_cast<const float4*>(p))

// d_ws layout (u16): [0..1024) W1p h-MFMA A-frags; [1024..9728) W2p B-frags.

// ============ kernel 1: fused {root-init | fragment-table prep} ============
__global__ __launch_bounds__(256) void prep_kernel(
    const float* __restrict__ x,
    const float* __restrict__ W1,      // [8,32]
    const float* __restrict__ b1,      // [32]
    const float* __restrict__ W2,      // [32,256]
    const float* __restrict__ b2,      // [256]
    const float* __restrict__ rootk,   // [16,16]
    const float* __restrict__ bias,    // [16]
    float* __restrict__ out,           // [N,16]
    unsigned short* __restrict__ tab,
    int n_nodes, int root_blocks)
{
    const int tid = threadIdx.x;
    const int bid = blockIdx.x;

    if (bid < root_blocks) {
        __shared__ float sR[256];
        __shared__ float sB[16];
        if (tid < 256) sR[tid] = rootk[tid];
        if (tid < 16)  sB[tid] = bias[tid];
        __syncthreads();

        int nid = bid * 256 + tid;
        if (nid >= n_nodes) return;

        const float* xp = x + (size_t)nid * 16;
        float xf[16];
#pragma unroll
        for (int f = 0; f < 16; f += 4) {
            float4 v = LD4(xp + f);
            xf[f] = v.x; xf[f + 1] = v.y; xf[f + 2] = v.z; xf[f + 3] = v.w;
        }
        float o[16];
#pragma unroll
        for (int cc = 0; cc < 16; ++cc) o[cc] = sB[cc];
#pragma unroll
        for (int f = 0; f < 16; ++f) {
            float p = xf[f];
#pragma unroll
            for (int cc = 0; cc < 16; ++cc)
                o[cc] = fmaf(p, sR[f * 16 + cc], o[cc]);
        }
        float* dst = out + (size_t)nid * 16;
#pragma unroll
        for (int cc = 0; cc < 16; cc += 4)
            *reinterpret_cast<float4*>(dst + cc) = make_float4(o[cc], o[cc+1], o[cc+2], o[cc+3]);
    } else {
        for (int it = tid; it < 64 * 19; it += 256) {
            int grp  = it >> 6;         // 0,1 -> W1p halves; 2..18 -> W2p steps
            int lane = it & 63;
            int q = lane >> 4, cc = lane & 15;
            union { unsigned short h[8]; uint4 u; } pk;
            if (grp < 2) {
                int hh = grp;
#pragma unroll
                for (int j = 0; j < 8; ++j) {
                    float v = 0.f;
                    if (q == 0)              v = W1[j * 32 + cc + 16 * hh];
                    else if (q == 1 && j==0) v = b1[cc + 16 * hh];
                    pk.h[j] = f2bf(v);
                }
                *reinterpret_cast<uint4*>(tab + ((size_t)hh * 64 + lane) * 8) = pk.u;
            } else {
                int s = grp - 2;        // K-step
#pragma unroll
                for (int j = 0; j < 8; ++j) {
                    float v;
                    if (s < 16) {
                        int hd = (j < 4) ? (4 * q + j) : (4 * q + 12 + j);  // perm
                        v = W2[hd * 256 + s * 16 + cc];
                    } else {
                        v = (q < 2) ? b2[(q * 8 + j) * 16 + cc] : 0.f;       // b2 fold
                    }
                    pk.h[j] = f2bf(v);
                }
                *reinterpret_cast<uint4*>(tab + 1024 + ((size_t)s * 64 + lane) * 8) = pk.u;
            }
        }
    }
}

// ============ kernel 2: MFMA edge kernel — 8-group runs, 3-deep rotating pipeline ============
template<int EXACT>
__global__ __launch_bounds__(256, 2) void edge_mfma_kernel(
    const float* __restrict__ x,       // [N,16]
    const float* __restrict__ efeat,   // [E,8]
    const int*   __restrict__ idx_i,
    const int*   __restrict__ idx_j,
    const unsigned short* __restrict__ tab,
    float* __restrict__ out,           // [N,16], pre-initialized with root term
    int n_edges, int n_groups)
{
    const int lane = threadIdx.x & 63;
    const int q = lane >> 4;
    const int c = lane & 15;

    // ---- per-wave fragment preload (registers) ----
    const bf16x8_t* w1f = reinterpret_cast<const bf16x8_t*>(tab) + lane;
    const bf16x8_t aW1_0 = w1f[0];
    const bf16x8_t aW1_1 = w1f[64];
    const bf16x8_t* w2f = reinterpret_cast<const bf16x8_t*>(tab + 1024) + lane;
    bf16x8_t bW2[17];
#pragma unroll
    for (int s = 0; s < 17; ++s) bW2[s] = w2f[s * 64];

    const unsigned int c1 = (q == 1) ? 0x00003F80u : 0u;   // bf16(1.0) one-hot for b1 row
    const bool isq0 = (q == 0);
    const bool qodd = (q & 1);
    float* const outc = out + c;

    const int wid = blockIdx.x * 4 + (threadIdx.x >> 6);
    const int g0  = wid * 8;
    if (g0 >= n_groups) return;
    const int rem = n_groups - g0;   // wave-uniform, >= 1

    // ---- all 8 source indices of the run in flight first ----
    const int* jp = idx_j + (size_t)g0 * 16 + c;
    int j0, j1, j2, j3, j4, j5, j6, j7;
    if (EXACT) {
        j0 = jp[0];
        j1 = (rem > 1) ? jp[16]  : 0;
        j2 = (rem > 2) ? jp[32]  : 0;
        j3 = (rem > 3) ? jp[48]  : 0;
        j4 = (rem > 4) ? jp[64]  : 0;
        j5 = (rem > 5) ? jp[80]  : 0;
        j6 = (rem > 6) ? jp[96]  : 0;
        j7 = (rem > 7) ? jp[112] : 0;
    } else {
        auto ldj = [&](int k) -> int {
            int eid = (g0 + k) * 16 + c;
            if (eid >= n_edges) eid = n_edges - 1;
            return idx_j[eid];
        };
        j0 = ldj(0);
        j1 = (rem > 1) ? ldj(1) : 0;
        j2 = (rem > 2) ? ldj(2) : 0;
        j3 = (rem > 3) ? ldj(3) : 0;
        j4 = (rem > 4) ? ldj(4) : 0;
        j5 = (rem > 5) ? ldj(5) : 0;
        j6 = (rem > 6) ? ldj(6) : 0;
        j7 = (rem > 7) ? ldj(7) : 0;
    }

    auto eptr = [&](int gg) -> const float* {
        int eid = gg * 16 + c;
        if (!EXACT) { if (eid >= n_edges) eid = n_edges - 1; }
        return efeat + (size_t)eid * 8;
    };

    auto compute = [&](float4 X0, float4 X1, float4 X2, float4 X3,
                       float4 E0, float4 E1, int gg) {
        // idx_i: issued now, consumed only at the very end (self-hiding)
        int t0, t1, t2, t3;
        if (EXACT || (gg * 16 + 16 <= n_edges)) {
            int4 tv = *reinterpret_cast<const int4*>(idx_i + gg * 16 + q * 4);
            t0 = tv.x; t1 = tv.y; t2 = tv.z; t3 = tv.w;
        } else {
            const int eb = gg * 16 + q * 4;
            t0 = (eb + 0 < n_edges) ? idx_i[eb + 0] : 0;
            t1 = (eb + 1 < n_edges) ? idx_i[eb + 1] : 0;
            t2 = (eb + 2 < n_edges) ? idx_i[eb + 2] : 0;
            t3 = (eb + 3 < n_edges) ? idx_i[eb + 3] : 0;
        }

        // ---- h via MFMA: lane owns hd {4q..4q+3, 4q+16..4q+19} ----
        union { bf16x8_t bf; unsigned int u[4]; } bB;
        bB.u[0] = isq0 ? cvt_pk_bf16(E0.x, E0.y) : c1;
        bB.u[1] = isq0 ? cvt_pk_bf16(E0.z, E0.w) : 0u;
        bB.u[2] = isq0 ? cvt_pk_bf16(E1.x, E1.y) : 0u;
        bB.u[3] = isq0 ? cvt_pk_bf16(E1.z, E1.w) : 0u;

        f32x4_t z4 = {0.f, 0.f, 0.f, 0.f};
        f32x4_t h0 = __builtin_amdgcn_mfma_f32_16x16x32_bf16(aW1_0, bB.bf, z4, 0, 0, 0);
        f32x4_t h1 = __builtin_amdgcn_mfma_f32_16x16x32_bf16(aW1_1, bB.bf, z4, 0, 0, 0);

        // relu'd h as packed f32 pairs (enables v_pk_mul_f32 in the K-loop)
        f32x2_t hp0, hp1, hp2, hp3;
        hp0[0] = fmaxf(h0[0], 0.f); hp0[1] = fmaxf(h0[1], 0.f);
        hp1[0] = fmaxf(h0[2], 0.f); hp1[1] = fmaxf(h0[3], 0.f);
        hp2[0] = fmaxf(h1[0], 0.f); hp2[1] = fmaxf(h1[1], 0.f);
        hp3[0] = fmaxf(h1[2], 0.f); hp3[1] = fmaxf(h1[3], 0.f);

        float xf[16];
        xf[0]=X0.x; xf[1]=X0.y; xf[2]=X0.z; xf[3]=X0.w;
        xf[4]=X1.x; xf[5]=X1.y; xf[6]=X1.z; xf[7]=X1.w;
        xf[8]=X2.x; xf[9]=X2.y; xf[10]=X2.z; xf[11]=X2.w;
        xf[12]=X3.x; xf[13]=X3.y; xf[14]=X3.z; xf[15]=X3.w;

        // ---- b2-fold A fragment ----
        union { bf16x8_t bf; unsigned int u[4]; } xb;
        xb.u[0] = cvt_pk_bf16(qodd ? xf[8]  : xf[0], qodd ? xf[9]  : xf[1]);
        xb.u[1] = cvt_pk_bf16(qodd ? xf[10] : xf[2], qodd ? xf[11] : xf[3]);
        xb.u[2] = cvt_pk_bf16(qodd ? xf[12] : xf[4], qodd ? xf[13] : xf[5]);
        xb.u[3] = cvt_pk_bf16(qodd ? xf[14] : xf[6], qodd ? xf[15] : xf[7]);

        // ---- K loop: A[c][q*8+j] = bf16(h[j] * x[f=s]), two acc chains ----
        f32x4_t acc0 = {0.f, 0.f, 0.f, 0.f};
        f32x4_t acc1 = {0.f, 0.f, 0.f, 0.f};
        union { bf16x8_t bf; unsigned int u[4]; } afr;
#pragma unroll
        for (int s = 0; s < 16; s += 2) {
            f32x2_t xs2; xs2[0] = xf[s]; xs2[1] = xf[s];
            f32x2_t p0 = hp0 * xs2, p1 = hp1 * xs2, p2 = hp2 * xs2, p3 = hp3 * xs2;
            afr.u[0] = cvt_pk_bf16(p0[0], p0[1]);
            afr.u[1] = cvt_pk_bf16(p1[0], p1[1]);
            afr.u[2] = cvt_pk_bf16(p2[0], p2[1]);
            afr.u[3] = cvt_pk_bf16(p3[0], p3[1]);
            acc0 = __builtin_amdgcn_mfma_f32_16x16x32_bf16(afr.bf, bW2[s], acc0, 0, 0, 0);
            xs2[0] = xf[s + 1]; xs2[1] = xf[s + 1];
            p0 = hp0 * xs2; p1 = hp1 * xs2; p2 = hp2 * xs2; p3 = hp3 * xs2;
            afr.u[0] = cvt_pk_bf16(p0[0], p0[1]);
            afr.u[1] = cvt_pk_bf16(p1[0], p1[1]);
            afr.u[2] = cvt_pk_bf16(p2[0], p2[1]);
            afr.u[3] = cvt_pk_bf16(p3[0], p3[1]);
            acc1 = __builtin_amdgcn_mfma_f32_16x16x32_bf16(afr.bf, bW2[s + 1], acc1, 0, 0, 0);
        }
        acc0 = __builtin_amdgcn_mfma_f32_16x16x32_bf16(xb.bf, bW2[16], acc0, 0, 0, 0);

        const float rr0 = acc0[0] + acc1[0];
        const float rr1 = acc0[1] + acc1[1];
        const float rr2 = acc0[2] + acc1[2];
        const float rr3 = acc0[3] + acc1[3];
        if (EXACT) {
            atomicAdd(outc + (size_t)t0 * 16, rr0);
            atomicAdd(outc + (size_t)t1 * 16, rr1);
            atomicAdd(outc + (size_t)t2 * 16, rr2);
            atomicAdd(outc + (size_t)t3 * 16, rr3);
        } else {
            const int eb = gg * 16 + q * 4;
            if (eb + 0 < n_edges) atomicAdd(outc + (size_t)t0 * 16, rr0);
            if (eb + 1 < n_edges) atomicAdd(outc + (size_t)t1 * 16, rr1);
            if (eb + 2 < n_edges) atomicAdd(outc + (size_t)t2 * 16, rr2);
            if (eb + 3 < n_edges) atomicAdd(outc + (size_t)t3 * 16, rr3);
        }
    };

#define STAGE(B0,B1,B2,B3,BE0,BE1, jv, gg)                         \
    {                                                              \
        const float* xp = x + (size_t)(jv) * 16;                   \
        B0 = LD4(xp); B1 = LD4(xp + 4);                            \
        B2 = LD4(xp + 8); B3 = LD4(xp + 12);                       \
        const float* ep = eptr(gg);                                \
        BE0 = LD4(ep); BE1 = LD4(ep + 4);                          \
    }

    float4 Ax0, Ax1, Ax2, Ax3, Ae0, Ae1;
    float4 Bx0, Bx1, Bx2, Bx3, Be0, Be1;
    float4 Cx0, Cx1, Cx2, Cx3, Ce0, Ce1;

    // ---- 3-deep rotating pipeline over 8 groups ----
    STAGE(Ax0,Ax1,Ax2,Ax3,Ae0,Ae1, j0, g0 + 0);
    if (rem > 1) STAGE(Bx0,Bx1,Bx2,Bx3,Be0,Be1, j1, g0 + 1);
    if (rem > 2) STAGE(Cx0,Cx1,Cx2,Cx3,Ce0,Ce1, j2, g0 + 2);

    compute(Ax0,Ax1,Ax2,Ax3,Ae0,Ae1, g0 + 0);
    if (rem > 3) STAGE(Ax0,Ax1,Ax2,Ax3,Ae0,Ae1, j3, g0 + 3);
    if (rem > 1) compute(Bx0,Bx1,Bx2,Bx3,Be0,Be1, g0 + 1);
    if (rem > 4) STAGE(Bx0,Bx1,Bx2,Bx3,Be0,Be1, j4, g0 + 4);
    if (rem > 2) compute(Cx0,Cx1,Cx2,Cx3,Ce0,Ce1, g0 + 2);
    if (rem > 5) STAGE(Cx0,Cx1,Cx2,Cx3,Ce0,Ce1, j5, g0 + 5);
    if (rem > 3) compute(Ax0,Ax1,Ax2,Ax3,Ae0,Ae1, g0 + 3);
    if (rem > 6) STAGE(Ax0,Ax1,Ax2,Ax3,Ae0,Ae1, j6, g0 + 6);
    if (rem > 4) compute(Bx0,Bx1,Bx2,Bx3,Be0,Be1, g0 + 4);
    if (rem > 7) STAGE(Bx0,Bx1,Bx2,Bx3,Be0,Be1, j7, g0 + 7);
    if (rem > 5) compute(Cx0,Cx1,Cx2,Cx3,Ce0,Ce1, g0 + 5);
    if (rem > 6) compute(Ax0,Ax1,Ax2,Ax3,Ae0,Ae1, g0 + 6);
    if (rem > 7) compute(Bx0,Bx1,Bx2,Bx3,Be0,Be1, g0 + 7);
#undef STAGE
}

extern "C" void kernel_launch(void* const* d_in, const int* in_sizes, int n_in,
                              void* d_out, int out_size, void* d_ws, size_t ws_size,
                              hipStream_t stream) {
    const float* x     = (const float*)d_in[0];
    const float* e     = (const float*)d_in[1];
    const int*   idx_i = (const int*)d_in[2];
    const int*   idx_j = (const int*)d_in[3];
    const float* W1    = (const float*)d_in[4];
    const float* b1    = (const float*)d_in[5];
    const float* W2    = (const float*)d_in[6];
    const float* b2    = (const float*)d_in[7];
    const float* rootk = (const float*)d_in[8];
    const float* bias  = (const float*)d_in[9];

    int n_nodes  = in_sizes[0] / 16;
    int n_edges  = in_sizes[2];
    int n_groups = (n_edges + 15) / 16;

    float* out = (float*)d_out;
    unsigned short* tab = (unsigned short*)d_ws;   // 19.5 KB used

    int root_blocks = (n_nodes + 255) / 256;
    prep_kernel<<<root_blocks + 1, 256, 0, stream>>>(x, W1, b1, W2, b2, rootk, bias,
                                                     out, tab, n_nodes, root_blocks);

    // 4 waves/block, 8 contiguous groups per wave
    int waves  = (n_groups + 7) / 8;
    int blocks = (waves + 3) / 4;
    if ((n_edges & 15) == 0)
        edge_mfma_kernel<1><<<blocks, 256, 0, stream>>>(x, e, idx_i, idx_j, tab, out,
                                                        n_edges, n_groups);
    else
        edge_mfma_kernel<0><<<blocks, 256, 0, stream>>>(x, e, idx_i, idx_j, tab, out,
                                                        n_edges, n_groups);
}

// Round 13
// 46.220 us; speedup vs baseline: 1.0349x; 1.0349x over previous
//
#include <hip/hip_runtime.h>

typedef __attribute__((ext_vector_type(8))) _Float16 f16x8_t;  // MFMA A/B operand (4 VGPRs)
typedef __attribute__((ext_vector_type(2))) _Float16 f16x2_t;  // packed f16 pair (1 VGPR)
typedef __attribute__((ext_vector_type(4))) float f32x4_t;     // MFMA accumulator

__device__ __forceinline__ f16x2_t pkh(float lo, float hi) {
    return __builtin_bit_cast(f16x2_t, __builtin_amdgcn_cvt_pkrtz(lo, hi));
}
__device__ __forceinline__ unsigned int pkrtz(float lo, float hi) {
    return __builtin_bit_cast(unsigned int, __builtin_amdgcn_cvt_pkrtz(lo, hi));
}

#define LD4(p) (*reinterpret_cast<const float4*>(p))

// d_ws layout (f16): [0..1024) W1p h-MFMA A-frags; [1024..9728) W2p B-frags.

// ============ kernel 1: fused {root-init | fragment-table prep} ============
__global__ __launch_bounds__(256) void prep_kernel(
    const float* __restrict__ x,
    const float* __restrict__ W1,      // [8,32]
    const float* __restrict__ b1,      // [32]
    const float* __restrict__ W2,      // [32,256]
    const float* __restrict__ b2,      // [256]
    const float* __restrict__ rootk,   // [16,16]
    const float* __restrict__ bias,    // [16]
    float* __restrict__ out,           // [N,16]
    _Float16* __restrict__ tab,
    int n_nodes, int root_blocks)
{
    const int tid = threadIdx.x;
    const int bid = blockIdx.x;

    if (bid < root_blocks) {
        __shared__ float sR[256];
        __shared__ float sB[16];
        if (tid < 256) sR[tid] = rootk[tid];
        if (tid < 16)  sB[tid] = bias[tid];
        __syncthreads();

        int nid = bid * 256 + tid;
        if (nid >= n_nodes) return;

        const float* xp = x + (size_t)nid * 16;
        float xf[16];
#pragma unroll
        for (int f = 0; f < 16; f += 4) {
            float4 v = LD4(xp + f);
            xf[f] = v.x; xf[f + 1] = v.y; xf[f + 2] = v.z; xf[f + 3] = v.w;
        }
        float o[16];
#pragma unroll
        for (int cc = 0; cc < 16; ++cc) o[cc] = sB[cc];
#pragma unroll
        for (int f = 0; f < 16; ++f) {
            float p = xf[f];
#pragma unroll
            for (int cc = 0; cc < 16; ++cc)
                o[cc] = fmaf(p, sR[f * 16 + cc], o[cc]);
        }
        float* dst = out + (size_t)nid * 16;
#pragma unroll
        for (int cc = 0; cc < 16; cc += 4)
            *reinterpret_cast<float4*>(dst + cc) = make_float4(o[cc], o[cc+1], o[cc+2], o[cc+3]);
    } else {
        for (int it = tid; it < 64 * 19; it += 256) {
            int grp  = it >> 6;         // 0,1 -> W1p halves; 2..18 -> W2p steps
            int lane = it & 63;
            int q = lane >> 4, cc = lane & 15;
            union { _Float16 h[8]; uint4 u; } pk;
            if (grp < 2) {
                int hh = grp;
#pragma unroll
                for (int j = 0; j < 8; ++j) {
                    float v = 0.f;
                    if (q == 0)              v = W1[j * 32 + cc + 16 * hh];
                    else if (q == 1 && j==0) v = b1[cc + 16 * hh];
                    pk.h[j] = (_Float16)v;
                }
                *reinterpret_cast<uint4*>(tab + ((size_t)hh * 64 + lane) * 8) = pk.u;
            } else {
                int s = grp - 2;        // K-step
#pragma unroll
                for (int j = 0; j < 8; ++j) {
                    float v;
                    if (s < 16) {
                        int hd = (j < 4) ? (4 * q + j) : (4 * q + 12 + j);  // perm
                        v = W2[hd * 256 + s * 16 + cc];
                    } else {
                        v = (q < 2) ? b2[(q * 8 + j) * 16 + cc] : 0.f;       // b2 fold
                    }
                    pk.h[j] = (_Float16)v;
                }
                *reinterpret_cast<uint4*>(tab + 1024 + ((size_t)s * 64 + lane) * 8) = pk.u;
            }
        }
    }
}

__device__ __forceinline__ float4 shfl4(float4 v, int src) {
    float4 r;
    r.x = __shfl(v.x, src); r.y = __shfl(v.y, src);
    r.z = __shfl(v.z, src); r.w = __shfl(v.w, src);
    return r;
}

// ============ kernel 2: f16 MFMA edge kernel — dedup gather, 4 groups/wave, 2-deep ============
template<int EXACT>
__global__ __launch_bounds__(256) void edge_mfma_kernel(
    const float* __restrict__ x,       // [N,16]
    const float* __restrict__ efeat,   // [E,8]
    const int*   __restrict__ idx_i,
    const int*   __restrict__ idx_j,
    const _Float16* __restrict__ tab,
    float* __restrict__ out,           // [N,16], pre-initialized with root term
    int n_edges, int n_groups)
{
    const int lane = threadIdx.x & 63;
    const int q = lane >> 4;
    const int c = lane & 15;

    // ---- per-wave fragment preload (registers, f16) ----
    const f16x8_t* w1f = reinterpret_cast<const f16x8_t*>(tab) + lane;
    const f16x8_t aW1_0 = w1f[0];
    const f16x8_t aW1_1 = w1f[64];
    const f16x8_t* w2f = reinterpret_cast<const f16x8_t*>(tab + 1024) + lane;
    f16x8_t bW2[17];
#pragma unroll
    for (int s = 0; s < 17; ++s) bW2[s] = w2f[s * 64];

    const unsigned int c1 = (q == 1) ? 0x00003C00u : 0u;   // f16(1.0) one-hot for b1 row
    const bool isq0 = (q == 0);
    const bool qodd = (q & 1);
    float* const outc = out + c;

    const int wid = blockIdx.x * 4 + (threadIdx.x >> 6);
    const int g0  = wid * 4;
    if (g0 >= n_groups) return;
    const int rem = n_groups - g0;   // >= 1, wave-uniform

    auto ldj = [&](int gg) -> int {
        int eid = gg * 16 + c;
        if (!EXACT) { if (eid >= n_edges) eid = n_edges - 1; }
        return idx_j[eid];
    };
    auto eptr = [&](int gg) -> const float* {
        int eid = gg * 16 + c;
        if (!EXACT) { if (eid >= n_edges) eid = n_edges - 1; }
        return efeat + (size_t)eid * 8;
    };

    auto compute = [&](float4 XQ, float4 E0, float4 E1, int gg) {
        // idx_i: issued now, consumed only at the very end (self-hiding)
        int t0, t1, t2, t3;
        if (EXACT || (gg * 16 + 16 <= n_edges)) {
            int4 tv = *reinterpret_cast<const int4*>(idx_i + gg * 16 + q * 4);
            t0 = tv.x; t1 = tv.y; t2 = tv.z; t3 = tv.w;
        } else {
            const int eb = gg * 16 + q * 4;
            t0 = (eb + 0 < n_edges) ? idx_i[eb + 0] : 0;
            t1 = (eb + 1 < n_edges) ? idx_i[eb + 1] : 0;
            t2 = (eb + 2 < n_edges) ? idx_i[eb + 2] : 0;
            t3 = (eb + 3 < n_edges) ? idx_i[eb + 3] : 0;
        }

        // ---- redistribute gather quarters: lane (q,c) holds quarter q of row j_c ----
        float4 X0 = shfl4(XQ, c);
        float4 X1 = shfl4(XQ, c + 16);
        float4 X2 = shfl4(XQ, c + 32);
        float4 X3 = shfl4(XQ, c + 48);

        // ---- h via MFMA (f16): lane owns hd {4q..4q+3, 4q+16..4q+19} ----
        union { f16x8_t v8; f16x2_t v2[4]; unsigned int u[4]; } bB;
        bB.u[0] = isq0 ? pkrtz(E0.x, E0.y) : c1;
        bB.u[1] = isq0 ? pkrtz(E0.z, E0.w) : 0u;
        bB.u[2] = isq0 ? pkrtz(E1.x, E1.y) : 0u;
        bB.u[3] = isq0 ? pkrtz(E1.z, E1.w) : 0u;

        f32x4_t z4 = {0.f, 0.f, 0.f, 0.f};
        f32x4_t h0 = __builtin_amdgcn_mfma_f32_16x16x32_f16(aW1_0, bB.v8, z4, 0, 0, 0);
        f32x4_t h1 = __builtin_amdgcn_mfma_f32_16x16x32_f16(aW1_1, bB.v8, z4, 0, 0, 0);

        // relu + pack h into f16 pairs
        f16x2_t hp0 = pkh(fmaxf(h0[0], 0.f), fmaxf(h0[1], 0.f));
        f16x2_t hp1 = pkh(fmaxf(h0[2], 0.f), fmaxf(h0[3], 0.f));
        f16x2_t hp2 = pkh(fmaxf(h1[0], 0.f), fmaxf(h1[1], 0.f));
        f16x2_t hp3 = pkh(fmaxf(h1[2], 0.f), fmaxf(h1[3], 0.f));

        float xf[16];
        xf[0]=X0.x; xf[1]=X0.y; xf[2]=X0.z; xf[3]=X0.w;
        xf[4]=X1.x; xf[5]=X1.y; xf[6]=X1.z; xf[7]=X1.w;
        xf[8]=X2.x; xf[9]=X2.y; xf[10]=X2.z; xf[11]=X2.w;
        xf[12]=X3.x; xf[13]=X3.y; xf[14]=X3.z; xf[15]=X3.w;

        // pre-duplicated x broadcasts: xss[f] = (x_f, x_f) in f16
        f16x2_t xss[16];
#pragma unroll
        for (int f = 0; f < 16; ++f)
            xss[f] = pkh(xf[f], xf[f]);

        // ---- b2-fold A fragment (pairs of adjacent x) ----
        union { f16x8_t v8; unsigned int u[4]; } xb;
        xb.u[0] = pkrtz(qodd ? xf[8]  : xf[0], qodd ? xf[9]  : xf[1]);
        xb.u[1] = pkrtz(qodd ? xf[10] : xf[2], qodd ? xf[11] : xf[3]);
        xb.u[2] = pkrtz(qodd ? xf[12] : xf[4], qodd ? xf[13] : xf[5]);
        xb.u[3] = pkrtz(qodd ? xf[14] : xf[6], qodd ? xf[15] : xf[7]);

        // ---- K loop: A[c][q*8+j] = h_j * x_s (v_pk_mul_f16), two acc chains ----
        f32x4_t acc0 = {0.f, 0.f, 0.f, 0.f};
        f32x4_t acc1 = {0.f, 0.f, 0.f, 0.f};
        union { f16x8_t v8; f16x2_t v2[4]; } afr;
#pragma unroll
        for (int s = 0; s < 16; s += 2) {
            f16x2_t xs2 = xss[s];
            afr.v2[0] = hp0 * xs2;
            afr.v2[1] = hp1 * xs2;
            afr.v2[2] = hp2 * xs2;
            afr.v2[3] = hp3 * xs2;
            acc0 = __builtin_amdgcn_mfma_f32_16x16x32_f16(afr.v8, bW2[s], acc0, 0, 0, 0);
            xs2 = xss[s + 1];
            afr.v2[0] = hp0 * xs2;
            afr.v2[1] = hp1 * xs2;
            afr.v2[2] = hp2 * xs2;
            afr.v2[3] = hp3 * xs2;
            acc1 = __builtin_amdgcn_mfma_f32_16x16x32_f16(afr.v8, bW2[s + 1], acc1, 0, 0, 0);
        }
        acc0 = __builtin_amdgcn_mfma_f32_16x16x32_f16(xb.v8, bW2[16], acc0, 0, 0, 0);

        const float rr0 = acc0[0] + acc1[0];
        const float rr1 = acc0[1] + acc1[1];
        const float rr2 = acc0[2] + acc1[2];
        const float rr3 = acc0[3] + acc1[3];
        if (EXACT) {
            atomicAdd(outc + (size_t)t0 * 16, rr0);
            atomicAdd(outc + (size_t)t1 * 16, rr1);
            atomicAdd(outc + (size_t)t2 * 16, rr2);
            atomicAdd(outc + (size_t)t3 * 16, rr3);
        } else {
            const int eb = gg * 16 + q * 4;
            if (eb + 0 < n_edges) atomicAdd(outc + (size_t)t0 * 16, rr0);
            if (eb + 1 < n_edges) atomicAdd(outc + (size_t)t1 * 16, rr1);
            if (eb + 2 < n_edges) atomicAdd(outc + (size_t)t2 * 16, rr2);
            if (eb + 3 < n_edges) atomicAdd(outc + (size_t)t3 * 16, rr3);
        }
    };

    // deduped stage: own 16B quarter of row j + e features
#define STAGE(BXQ, BE0, BE1, jv, gg)                                \
    {                                                               \
        BXQ = LD4(x + (size_t)(jv) * 16 + q * 4);                   \
        const float* ep = eptr(gg);                                 \
        BE0 = LD4(ep); BE1 = LD4(ep + 4);                           \
    }

    // ---- all 4 source indices in flight first ----
    const int jA = ldj(g0);
    const int jB = (rem > 1) ? ldj(g0 + 1) : 0;
    const int jC = (rem > 2) ? ldj(g0 + 2) : 0;
    const int jD = (rem > 3) ? ldj(g0 + 3) : 0;

    float4 aq, ae0, ae1;
    float4 bq, be0, be1;

    STAGE(aq, ae0, ae1, jA, g0);
    if (rem > 1) STAGE(bq, be0, be1, jB, g0 + 1);
    compute(aq, ae0, ae1, g0);
    if (rem > 1) {
        if (rem > 2) STAGE(aq, ae0, ae1, jC, g0 + 2);
        compute(bq, be0, be1, g0 + 1);
        if (rem > 2) {
            if (rem > 3) STAGE(bq, be0, be1, jD, g0 + 3);
            compute(aq, ae0, ae1, g0 + 2);
            if (rem > 3) compute(bq, be0, be1, g0 + 3);
        }
    }
#undef STAGE
}

extern "C" void kernel_launch(void* const* d_in, const int* in_sizes, int n_in,
                              void* d_out, int out_size, void* d_ws, size_t ws_size,
                              hipStream_t stream) {
    const float* x     = (const float*)d_in[0];
    const float* e     = (const float*)d_in[1];
    const int*   idx_i = (const int*)d_in[2];
    const int*   idx_j = (const int*)d_in[3];
    const float* W1    = (const float*)d_in[4];
    const float* b1    = (const float*)d_in[5];
    const float* W2    = (const float*)d_in[6];
    const float* b2    = (const float*)d_in[7];
    const float* rootk = (const float*)d_in[8];
    const float* bias  = (const float*)d_in[9];

    int n_nodes  = in_sizes[0] / 16;
    int n_edges  = in_sizes[2];
    int n_groups = (n_edges + 15) / 16;

    float* out = (float*)d_out;
    _Float16* tab = (_Float16*)d_ws;   // 19.5 KB used

    int root_blocks = (n_nodes + 255) / 256;
    prep_kernel<<<root_blocks + 1, 256, 0, stream>>>(x, W1, b1, W2, b2, rootk, bias,
                                                     out, tab, n_nodes, root_blocks);

    // 4 waves/block, 4 contiguous groups per wave
    int blocks = (n_groups + 15) / 16;
    if ((n_edges & 15) == 0)
        edge_mfma_kernel<1><<<blocks, 256, 0, stream>>>(x, e, idx_i, idx_j, tab, out,
                                                        n_edges, n_groups);
    else
        edge_mfma_kernel<0><<<blocks, 256, 0, stream>>>(x, e, idx_i, idx_j, tab, out,
                                                        n_edges, n_groups);
}